// Round 20
// baseline (67.113 us; speedup 1.0000x reference)
//
#include <hip/hip_runtime.h>

constexpr int Bn = 64, T = 256, C = 384, H = 6, D = 64;
constexpr int BT = Bn * T;          // 16384
constexpr int NQKV = 3 * C;         // 1152
constexpr int WALL_ELEMS = NQKV * C; // 442368
constexpr int WP_ELEMS = C * C;      // 147456

using f32x4 = __attribute__((ext_vector_type(4))) float;
using fvec4 = __attribute__((ext_vector_type(4))) float;
using us4   = __attribute__((ext_vector_type(4))) unsigned short;
using us8   = __attribute__((ext_vector_type(8))) unsigned short;
using bf8   = __attribute__((ext_vector_type(8))) __bf16;

__device__ __forceinline__ unsigned short f2bf(float f) {
  unsigned u = __builtin_bit_cast(unsigned, f);
  u += 0x7FFFu + ((u >> 16) & 1u);   // RNE; inputs are never NaN here
  return (unsigned short)(u >> 16);
}

__device__ __forceinline__ f32x4 mfma16(us8 a, us8 b, f32x4 c) {
  return __builtin_amdgcn_mfma_f32_16x16x32_bf16(
      __builtin_bit_cast(bf8, a), __builtin_bit_cast(bf8, b), c, 0, 0, 0);
}

__device__ __forceinline__ void glds16(const unsigned short* g,
                                       unsigned short* l) {
  __builtin_amdgcn_global_load_lds(
      (const __attribute__((address_space(1))) unsigned int*)g,
      (__attribute__((address_space(3))) unsigned int*)l, 16, 0, 0);
}

// ---------------------------------------------------------------------------
// Prep (one launch): blocks 0..107 transpose Wq/Wk/Wv -> Wall_t[n][c];
// blocks 108..179 cast Wp -> Wpb; blocks 180..3251 cast x -> Xb.
// ---------------------------------------------------------------------------
__global__ __launch_bounds__(256) void k_prep(
    const float* __restrict__ x,
    const float* __restrict__ Wq, const float* __restrict__ Wk,
    const float* __restrict__ Wv, const float* __restrict__ Wp,
    unsigned short* __restrict__ Wall, unsigned short* __restrict__ Wpb,
    unsigned short* __restrict__ Xb) {
  __shared__ unsigned short t[64][71];
  const int bid = blockIdx.x;
  const int tid = threadIdx.x;
  if (bid < 108) {
    const int ct = bid % 6, ph = bid / 6;
    const int h = ph % 6, p = ph / 6;
    const float* W = (p == 0) ? Wq : (p == 1) ? Wk : Wv;
    const int c0 = ct * 64;
    const int d = tid & 63, cq = tid >> 6;
#pragma unroll
    for (int s = 0; s < 16; ++s) {
      const int c_loc = cq * 16 + s;
      t[c_loc][d] = f2bf(W[(size_t)(h * C + c0 + c_loc) * D + d]);
    }
    __syncthreads();
    const int d_loc = tid >> 2, ch = tid & 3;
#pragma unroll
    for (int it = 0; it < 2; ++it) {
      const int cc = (ch + it * 4) * 8;
      us8 o;
#pragma unroll
      for (int j = 0; j < 8; ++j) o[j] = t[cc + j][d_loc];
      *(us8*)&Wall[(size_t)(p * C + h * D + d_loc) * C + c0 + cc] = o;
    }
  } else {
    const float* src;
    unsigned short* dst;
    int off;
    if (bid < 180) { src = Wp; dst = Wpb; off = (bid - 108) * 2048 + tid * 8; }
    else           { src = x;  dst = Xb;  off = (bid - 180) * 2048 + tid * 8; }
    fvec4 a = *(const fvec4*)(src + off);
    fvec4 b = *(const fvec4*)(src + off + 4);
    us8 o;
#pragma unroll
    for (int j = 0; j < 4; ++j) { o[j] = f2bf(a[j]); o[4 + j] = f2bf(b[j]); }
    *(us8*)(dst + off) = o;
  }
}

// ---------------------------------------------------------------------------
// Staging for 128-row x 64-col bf16 tiles (16KB): global_load_lds w=16,
// XOR-swizzled SOURCE (LDS chunk position c holds global chunk c^(row&7);
// linear LDS dest). 4 instructions per thread.
// ---------------------------------------------------------------------------
__device__ __forceinline__ void stage_tile(
    const unsigned short* __restrict__ g, unsigned short* l,
    int row0g, int k0, int tr, int tc, int w) {
#pragma unroll
  for (int s = 0; s < 4; ++s) {
    const int row = s * 32 + tr;                  // tr = tid>>3 (0..31)
    const int sc = (tc ^ (row & 7)) * 8;          // tc = tid&7
    glds16(g + (size_t)(row0g + row) * C + k0 + sc,
           l + (s * 32 + w * 8) * 64);            // wave-uniform base
  }
}

// 64-row x 64-col tile (8KB): 2 instructions per thread.
__device__ __forceinline__ void stage_tile64(
    const unsigned short* __restrict__ g, unsigned short* l,
    int row0g, int k0, int tr, int tc, int w) {
#pragma unroll
  for (int s = 0; s < 2; ++s) {
    const int row = s * 32 + tr;
    const int sc = (tc ^ (row & 7)) * 8;
    glds16(g + (size_t)(row0g + row) * C + k0 + sc,
           l + (s * 32 + w * 8) * 64);
  }
}

// ---------------------------------------------------------------------------
// QKV GEMM: double-buffered 128x128, BK=64, counted-vmcnt (R10/R14-proven).
// A=Xb, B=Wall -> QKV bf16 (Q pre-scaled by 0.125*log2e; V -> VT transposed).
// ---------------------------------------------------------------------------
__global__ __launch_bounds__(256) void k_gemm0(
    const unsigned short* __restrict__ A, const unsigned short* __restrict__ Bm,
    unsigned short* __restrict__ QKV, unsigned short* __restrict__ VT) {
  constexpr int BK = 64, NT = C / BK;   // 6 K-steps
  __shared__ unsigned short Al[2][128 * BK];
  __shared__ unsigned short Bl[2][128 * BK];
  const int nwg = gridDim.x;            // 1152
  const int bid = blockIdx.x;
  const int lin = (bid & 7) * (nwg >> 3) + (bid >> 3);  // bijective (nwg%8==0)
  const int m0 = (lin / 9) * 128, n0 = (lin % 9) * 128;
  const int tid = threadIdx.x;
  const int w = tid >> 6, lane = tid & 63;
  const int lr = lane & 15, lg = lane >> 4;
  const int wm = (w >> 1) * 64, wn = (w & 1) * 64;
  const int tr = tid >> 3, tc = tid & 7;

  f32x4 acc[4][4];
#pragma unroll
  for (int i = 0; i < 4; ++i)
#pragma unroll
    for (int j = 0; j < 4; ++j) acc[i][j] = (f32x4){0.f, 0.f, 0.f, 0.f};

  stage_tile(A, &Al[0][0], m0, 0, tr, tc, w);
  stage_tile(Bm, &Bl[0][0], n0, 0, tr, tc, w);
  stage_tile(A, &Al[1][0], m0, BK, tr, tc, w);
  stage_tile(Bm, &Bl[1][0], n0, BK, tr, tc, w);

  int cur = 0;
  for (int t = 0; t < NT; ++t) {
    if (t < NT - 1) {
      asm volatile("s_waitcnt vmcnt(8)" ::: "memory");  // buf[cur] landed
    } else {
      asm volatile("s_waitcnt vmcnt(0)" ::: "memory");
    }
    asm volatile("s_barrier" ::: "memory");
#pragma unroll
    for (int kc = 0; kc < 2; ++kc) {
      us8 af[4], bfr[4];
#pragma unroll
      for (int i = 0; i < 4; ++i) {
        const int ra = wm + i * 16 + lr;
        af[i] = *(const us8*)&Al[cur][ra * 64 + (((kc * 4 + lg) ^ (ra & 7)) * 8)];
        const int rb = wn + i * 16 + lr;
        bfr[i] = *(const us8*)&Bl[cur][rb * 64 + (((kc * 4 + lg) ^ (rb & 7)) * 8)];
      }
#pragma unroll
      for (int i = 0; i < 4; ++i)
#pragma unroll
        for (int j = 0; j < 4; ++j)
          acc[i][j] = mfma16(af[i], bfr[j], acc[i][j]);
    }
    asm volatile("s_barrier" ::: "memory");
    if (t + 2 < NT) {
      stage_tile(A, &Al[cur][0], m0, (t + 2) * BK, tr, tc, w);
      stage_tile(Bm, &Bl[cur][0], n0, (t + 2) * BK, tr, tc, w);
    }
    cur ^= 1;
  }

  // epilogue: C/D frag row=(lane>>4)*4+r, col=lane&15
  if (n0 < 2 * C) {  // Q,K region (Q scaled into log2 domain)
    const float scl = (n0 < C) ? 0.18033688f : 1.0f;  // 0.125 * log2(e)
#pragma unroll
    for (int i = 0; i < 4; ++i)
#pragma unroll
      for (int j = 0; j < 4; ++j) {
        const int col = n0 + wn + j * 16 + lr;
#pragma unroll
        for (int r = 0; r < 4; ++r) {
          const size_t row = m0 + wm + i * 16 + lg * 4 + r;
          QKV[row * NQKV + col] = f2bf(acc[i][j][r] * scl);
        }
      }
  } else {           // V region: store transposed VT[b][h][d][t]
#pragma unroll
    for (int i = 0; i < 4; ++i)
#pragma unroll
      for (int j = 0; j < 4; ++j) {
        const int vcol = n0 + wn + j * 16 + lr - 2 * C;
        const int h = vcol >> 6, d = vcol & 63;
        const int row0 = m0 + wm + i * 16 + lg * 4;
        const int b = row0 >> 8, tq = row0 & 255;
        us4 o4;
#pragma unroll
        for (int r = 0; r < 4; ++r) o4[r] = f2bf(acc[i][j][r]);
        *(us4*)&VT[(((size_t)b * H + h) * D + d) * T + tq] = o4;
      }
  }
}

// ---------------------------------------------------------------------------
// Output projection GEMM, retiled 64x128 (768 blocks -> balanced 3 blocks/CU,
// LDS 48KB, 12 waves/CU). Same counted-vmcnt template; waves 2x2, each 32x64
// (acc[2][4]). Prologue 12 outstanding -> steady vmcnt(6).
// ---------------------------------------------------------------------------
__global__ __launch_bounds__(256) void k_gemm1(
    const unsigned short* __restrict__ A, const unsigned short* __restrict__ Bm,
    const float* __restrict__ bias, float* __restrict__ Of) {
  constexpr int BK = 64, NT = C / BK;   // 6 K-steps
  __shared__ unsigned short Al[2][64 * BK];    // 16 KB
  __shared__ unsigned short Bl[2][128 * BK];   // 32 KB
  const int nwg = gridDim.x;            // 768
  const int bid = blockIdx.x;
  const int lin = (bid & 7) * (nwg >> 3) + (bid >> 3);  // bijective
  const int m0 = (lin / 3) * 64, n0 = (lin % 3) * 128;
  const int tid = threadIdx.x;
  const int w = tid >> 6, lane = tid & 63;
  const int lr = lane & 15, lg = lane >> 4;
  const int wm = (w >> 1) * 32, wn = (w & 1) * 64;
  const int tr = tid >> 3, tc = tid & 7;

  f32x4 acc[2][4];
#pragma unroll
  for (int i = 0; i < 2; ++i)
#pragma unroll
    for (int j = 0; j < 4; ++j) acc[i][j] = (f32x4){0.f, 0.f, 0.f, 0.f};

  // prologue: two tiles in flight (12 glds/thread outstanding)
  stage_tile64(A, &Al[0][0], m0, 0, tr, tc, w);
  stage_tile(Bm, &Bl[0][0], n0, 0, tr, tc, w);
  stage_tile64(A, &Al[1][0], m0, BK, tr, tc, w);
  stage_tile(Bm, &Bl[1][0], n0, BK, tr, tc, w);

  int cur = 0;
  for (int t = 0; t < NT; ++t) {
    if (t < NT - 1) {
      asm volatile("s_waitcnt vmcnt(6)" ::: "memory");  // buf[cur] landed
    } else {
      asm volatile("s_waitcnt vmcnt(0)" ::: "memory");
    }
    asm volatile("s_barrier" ::: "memory");
#pragma unroll
    for (int kc = 0; kc < 2; ++kc) {
      us8 af[2], bfr[4];
#pragma unroll
      for (int i = 0; i < 2; ++i) {
        const int ra = wm + i * 16 + lr;
        af[i] = *(const us8*)&Al[cur][ra * 64 + (((kc * 4 + lg) ^ (ra & 7)) * 8)];
      }
#pragma unroll
      for (int j = 0; j < 4; ++j) {
        const int rb = wn + j * 16 + lr;
        bfr[j] = *(const us8*)&Bl[cur][rb * 64 + (((kc * 4 + lg) ^ (rb & 7)) * 8)];
      }
#pragma unroll
      for (int i = 0; i < 2; ++i)
#pragma unroll
        for (int j = 0; j < 4; ++j)
          acc[i][j] = mfma16(af[i], bfr[j], acc[i][j]);
    }
    asm volatile("s_barrier" ::: "memory");
    if (t + 2 < NT) {
      stage_tile64(A, &Al[cur][0], m0, (t + 2) * BK, tr, tc, w);
      stage_tile(Bm, &Bl[cur][0], n0, (t + 2) * BK, tr, tc, w);
    }
    cur ^= 1;
  }

#pragma unroll
  for (int i = 0; i < 2; ++i)
#pragma unroll
    for (int j = 0; j < 4; ++j) {
      const int col = n0 + wn + j * 16 + lr;
      const float bv = bias[col];
#pragma unroll
      for (int r = 0; r < 4; ++r) {
        const size_t row = m0 + wm + i * 16 + lg * 4 + r;
        Of[row * C + col] = acc[i][j][r] + bv;
      }
    }
}

// ---------------------------------------------------------------------------
// Fused causal attention, 2-tile flash pipeline (R14-proven) + s_setprio
// around MFMA clusters (attn-isolated: m191 +4-7%; R11's regression was the
// GEMM setprio, not attn).
// ---------------------------------------------------------------------------
__global__ __launch_bounds__(512, 4) void k_attn(
    const unsigned short* __restrict__ QKV, const unsigned short* __restrict__ VT,
    unsigned short* __restrict__ Y) {
  __shared__ unsigned short Kl[2][128][64];   // 32KB
  __shared__ unsigned short Vl[2][64][128];   // 32KB
  __shared__ unsigned short Pch[8][16][32];   // 8KB
  const int bid = blockIdx.x;
  const int lin = (bid & 7) * 96 + (bid >> 3);   // bijective: 768 % 8 == 0
  const int b = lin / 12, rr = lin % 12;
  const int h = rr >> 1, qt = rr & 1;
  const int t0 = qt * 128;
  const int nt = qt + 1;
  const int tid = threadIdx.x;
  const int w = tid >> 6, lane = tid & 63;
  const int lr = lane & 15, lg = lane >> 4;
  const int xk = lr & 7;

  // ---- Q fragments first (oldest in vmcnt FIFO) ----
  const size_t qbase = (size_t)(b * T + t0 + w * 16 + lr) * NQKV + h * D;
  const us8 aq0 = *(const us8*)(QKV + qbase + lg * 8);
  const us8 aq1 = *(const us8*)(QKV + qbase + 32 + lg * 8);
  asm volatile("" ::: "memory");   // pin: Q loads issue before staging glds

  const unsigned short* kgbase = QKV + (size_t)(b * T) * NQKV + C + h * D;
  const unsigned short* vbase = VT + ((size_t)b * H + h) * D * T;

  auto stage_kv = [&](int tt) {
#pragma unroll
    for (int s = 0; s < 2; ++s) {
      const int row = s * 64 + w * 8 + (lane >> 3);       // 0..127 in tile
      glds16(kgbase + (size_t)(tt * 128 + row) * NQKV + ((lane & 7) ^ (row & 7)) * 8,
             &Kl[tt][s * 64 + w * 8][0]);
    }
#pragma unroll
    for (int s = 0; s < 2; ++s) {
      const int d = s * 32 + w * 4 + (lane >> 4);          // 0..63
      glds16(vbase + (size_t)d * T + tt * 128 + (((lane & 15) ^ (d & 7)) * 8),
             &Vl[tt][s * 32 + w * 4][0]);
    }
  };

  stage_kv(0);
  if (nt == 2) stage_kv(1);

  if (nt == 2) asm volatile("s_waitcnt vmcnt(4)" ::: "memory");  // tile0 ready
  else         asm volatile("s_waitcnt vmcnt(0)" ::: "memory");
  asm volatile("s_barrier" ::: "memory");

  // ---- running softmax state (log2 domain) ----
  float m[4] = {-1e30f, -1e30f, -1e30f, -1e30f};
  float l[4] = {0.f, 0.f, 0.f, 0.f};
  f32x4 o[4];
#pragma unroll
  for (int nf = 0; nf < 4; ++nf) o[nf] = (f32x4){0.f, 0.f, 0.f, 0.f};

  auto process_tile = [&](int tt, bool need_mask) {
    // S = Q K^T over this 128-col tile (already log2-scaled via Q)
    f32x4 s[8];
#pragma unroll
    for (int sf = 0; sf < 8; ++sf) s[sf] = (f32x4){0.f, 0.f, 0.f, 0.f};
    __builtin_amdgcn_s_setprio(1);
#pragma unroll
    for (int sf = 0; sf < 8; ++sf) {
      us8 kb0 = *(const us8*)&Kl[tt][sf * 16 + lr][(lg ^ xk) * 8];
      s[sf] = mfma16(aq0, kb0, s[sf]);
      us8 kb1 = *(const us8*)&Kl[tt][sf * 16 + lr][((4 + lg) ^ xk) * 8];
      s[sf] = mfma16(aq1, kb1, s[sf]);
    }
    __builtin_amdgcn_s_setprio(0);
    // causal mask (uniform-skippable) + tile row-max
    float tm[4] = {-1e30f, -1e30f, -1e30f, -1e30f};
#pragma unroll
    for (int sf = 0; sf < 8; ++sf) {
#pragma unroll
      for (int r = 0; r < 4; ++r) {
        float v = s[sf][r];
        if (need_mask) {
          const int trow = t0 + w * 16 + lg * 4 + r;
          const int scol = tt * 128 + sf * 16 + lr;
          if (scol > trow) v = -1e30f;
          s[sf][r] = v;
        }
        tm[r] = fmaxf(tm[r], v);
      }
    }
#pragma unroll
    for (int dd = 1; dd < 16; dd <<= 1)
#pragma unroll
      for (int r = 0; r < 4; ++r)
        tm[r] = fmaxf(tm[r], __shfl_xor(tm[r], dd, 64));
    // online update: new max, rescale factor (base 2)
    float fac[4];
#pragma unroll
    for (int r = 0; r < 4; ++r) {
      const float mn = fmaxf(m[r], tm[r]);
      fac[r] = __builtin_amdgcn_exp2f(m[r] - mn);
      m[r] = mn;
    }
    // exp2 + tile row-sum
    float ts[4] = {0.f, 0.f, 0.f, 0.f};
#pragma unroll
    for (int sf = 0; sf < 8; ++sf) {
#pragma unroll
      for (int r = 0; r < 4; ++r) {
        float p = __builtin_amdgcn_exp2f(s[sf][r] - m[r]);
        s[sf][r] = p;
        ts[r] += p;
      }
    }
#pragma unroll
    for (int dd = 1; dd < 16; dd <<= 1)
#pragma unroll
      for (int r = 0; r < 4; ++r)
        ts[r] += __shfl_xor(ts[r], dd, 64);
#pragma unroll
    for (int r = 0; r < 4; ++r) l[r] = l[r] * fac[r] + ts[r];
#pragma unroll
    for (int nf = 0; nf < 4; ++nf)
#pragma unroll
      for (int r = 0; r < 4; ++r) o[nf][r] *= fac[r];
    // O += P V over 4 32-col chunks
#pragma unroll
    for (int kk = 0; kk < 4; ++kk) {
#pragma unroll
      for (int half = 0; half < 2; ++half) {
        const int sf = kk * 2 + half;
        const int row = lg * 4;
#pragma unroll
        for (int r = 0; r < 4; ++r) {
          const int cch = (half * 2 + (lr >> 3)) ^ ((row + r) & 3);
          Pch[w][row + r][cch * 8 + (lr & 7)] = f2bf(s[sf][r]);
        }
      }
      __builtin_amdgcn_wave_barrier();
      us8 pa = *(const us8*)&Pch[w][lr][(lg ^ (lr & 3)) * 8];
      __builtin_amdgcn_wave_barrier();
      __builtin_amdgcn_s_setprio(1);
#pragma unroll
      for (int nf = 0; nf < 4; ++nf) {
        us8 bv = *(const us8*)&Vl[tt][nf * 16 + lr][((kk * 4 + lg) ^ xk) * 8];
        o[nf] = mfma16(pa, bv, o[nf]);
      }
      __builtin_amdgcn_s_setprio(0);
    }
  };

  process_tile(0, qt == 0);
  if (nt == 2) {
    asm volatile("s_waitcnt vmcnt(0)" ::: "memory");  // tile1 landed
    asm volatile("s_barrier" ::: "memory");           // all waves' glds visible
    process_tile(1, true);
  }

  // ---- normalize + store ----
  float rs[4];
#pragma unroll
  for (int r = 0; r < 4; ++r) rs[r] = 1.0f / l[r];
#pragma unroll
  for (int nf = 0; nf < 4; ++nf)
#pragma unroll
    for (int r = 0; r < 4; ++r) {
      const int trow = t0 + w * 16 + lg * 4 + r;
      Y[(size_t)(b * T + trow) * C + h * D + nf * 16 + lr] =
          f2bf(o[nf][r] * rs[r]);
    }
}

extern "C" void kernel_launch(void* const* d_in, const int* in_sizes, int n_in,
                              void* d_out, int out_size, void* d_ws, size_t ws_size,
                              hipStream_t stream) {
  const float* x  = (const float*)d_in[0];
  const float* Wq = (const float*)d_in[1];
  const float* Wk = (const float*)d_in[2];
  const float* Wv = (const float*)d_in[3];
  const float* Wp = (const float*)d_in[4];
  const float* bp = (const float*)d_in[5];
  float* out = (float*)d_out;

  unsigned short* Wall = (unsigned short*)d_ws;             //   884,736 B
  unsigned short* Wpb  = Wall + WALL_ELEMS;                 //   294,912 B
  unsigned short* QKV  = Wpb + WP_ELEMS;                    //  37,748,736 B
  unsigned short* Yb   = QKV + (size_t)BT * NQKV;           //  12,582,912 B
  unsigned short* VT   = Yb + (size_t)BT * C;               //  12,582,912 B
  unsigned short* Xb   = Yb;  // alias: Xb dead before k_attn writes Yb

  k_prep<<<180 + BT * C / 2048, 256, 0, stream>>>(x, Wq, Wk, Wv, Wp,
                                                  Wall, Wpb, Xb);
  k_gemm0<<<NQKV / 128 * (BT / 128), 256, 0, stream>>>(Xb, Wall, QKV, VT);
  k_attn<<<T / 128 * H * Bn, 512, 0, stream>>>(QKV, VT, Yb);
  k_gemm1<<<C / 128 * (BT / 64), 256, 0, stream>>>(Yb, Wpb, bp, out);
}

// Round 21
// 66.813 us; speedup vs baseline: 1.0045x; 1.0045x over previous
//
#include <hip/hip_runtime.h>

constexpr int Bn = 64, T = 256, C = 384, H = 6, D = 64;
constexpr int BT = Bn * T;          // 16384
constexpr int NQKV = 3 * C;         // 1152
constexpr int WALL_ELEMS = NQKV * C; // 442368
constexpr int WP_ELEMS = C * C;      // 147456

using f32x4 = __attribute__((ext_vector_type(4))) float;
using fvec4 = __attribute__((ext_vector_type(4))) float;
using us4   = __attribute__((ext_vector_type(4))) unsigned short;
using us8   = __attribute__((ext_vector_type(8))) unsigned short;
using bf8   = __attribute__((ext_vector_type(8))) __bf16;

__device__ __forceinline__ unsigned short f2bf(float f) {
  unsigned u = __builtin_bit_cast(unsigned, f);
  u += 0x7FFFu + ((u >> 16) & 1u);   // RNE; inputs are never NaN here
  return (unsigned short)(u >> 16);
}

__device__ __forceinline__ f32x4 mfma16(us8 a, us8 b, f32x4 c) {
  return __builtin_amdgcn_mfma_f32_16x16x32_bf16(
      __builtin_bit_cast(bf8, a), __builtin_bit_cast(bf8, b), c, 0, 0, 0);
}

__device__ __forceinline__ void glds16(const unsigned short* g,
                                       unsigned short* l) {
  __builtin_amdgcn_global_load_lds(
      (const __attribute__((address_space(1))) unsigned int*)g,
      (__attribute__((address_space(3))) unsigned int*)l, 16, 0, 0);
}

// ---------------------------------------------------------------------------
// Prep (one launch): blocks 0..107 transpose Wq/Wk/Wv -> Wall_t[n][c];
// blocks 108..179 cast Wp -> Wpb; blocks 180..3251 cast x -> Xb.
// ---------------------------------------------------------------------------
__global__ __launch_bounds__(256) void k_prep(
    const float* __restrict__ x,
    const float* __restrict__ Wq, const float* __restrict__ Wk,
    const float* __restrict__ Wv, const float* __restrict__ Wp,
    unsigned short* __restrict__ Wall, unsigned short* __restrict__ Wpb,
    unsigned short* __restrict__ Xb) {
  __shared__ unsigned short t[64][71];
  const int bid = blockIdx.x;
  const int tid = threadIdx.x;
  if (bid < 108) {
    const int ct = bid % 6, ph = bid / 6;
    const int h = ph % 6, p = ph / 6;
    const float* W = (p == 0) ? Wq : (p == 1) ? Wk : Wv;
    const int c0 = ct * 64;
    const int d = tid & 63, cq = tid >> 6;
#pragma unroll
    for (int s = 0; s < 16; ++s) {
      const int c_loc = cq * 16 + s;
      t[c_loc][d] = f2bf(W[(size_t)(h * C + c0 + c_loc) * D + d]);
    }
    __syncthreads();
    const int d_loc = tid >> 2, ch = tid & 3;
#pragma unroll
    for (int it = 0; it < 2; ++it) {
      const int cc = (ch + it * 4) * 8;
      us8 o;
#pragma unroll
      for (int j = 0; j < 8; ++j) o[j] = t[cc + j][d_loc];
      *(us8*)&Wall[(size_t)(p * C + h * D + d_loc) * C + c0 + cc] = o;
    }
  } else {
    const float* src;
    unsigned short* dst;
    int off;
    if (bid < 180) { src = Wp; dst = Wpb; off = (bid - 108) * 2048 + tid * 8; }
    else           { src = x;  dst = Xb;  off = (bid - 180) * 2048 + tid * 8; }
    fvec4 a = *(const fvec4*)(src + off);
    fvec4 b = *(const fvec4*)(src + off + 4);
    us8 o;
#pragma unroll
    for (int j = 0; j < 4; ++j) { o[j] = f2bf(a[j]); o[4 + j] = f2bf(b[j]); }
    *(us8*)(dst + off) = o;
  }
}

// ---------------------------------------------------------------------------
// Staging for BK=64 tiles (128 rows x 64 cols bf16 = 16KB): global_load_lds
// w=16, XOR-swizzled SOURCE (LDS chunk position c holds global chunk
// c^(row&7); linear LDS dest). 4 instructions per thread per tile.
// ---------------------------------------------------------------------------
__device__ __forceinline__ void stage_tile(
    const unsigned short* __restrict__ g, unsigned short* l,
    int row0g, int k0, int tr, int tc, int w) {
#pragma unroll
  for (int s = 0; s < 4; ++s) {
    const int row = s * 32 + tr;                  // tr = tid>>3 (0..31)
    const int sc = (tc ^ (row & 7)) * 8;          // tc = tid&7
    glds16(g + (size_t)(row0g + row) * C + k0 + sc,
           l + (s * 32 + w * 8) * 64);            // wave-uniform base
  }
}

// ---------------------------------------------------------------------------
// Double-buffered 128x128 GEMM, BK=64, counted-vmcnt pipeline (R10/R14-proven
// best). MODE 0: A=Xb, B=Wall -> QKV bf16 (Q pre-scaled by 0.125*log2e;
// V transposed into VT). MODE 1: A=Yb, B=Wpb -> out f32 + bias.
// ---------------------------------------------------------------------------
template <int MODE>
__global__ __launch_bounds__(256) void k_gemm(
    const unsigned short* __restrict__ A, const unsigned short* __restrict__ Bm,
    const float* __restrict__ bias, unsigned short* __restrict__ QKV,
    unsigned short* __restrict__ VT, float* __restrict__ Of, int nwgn) {
  constexpr int BK = 64, NT = C / BK;   // 6 K-steps
  __shared__ unsigned short Al[2][128 * BK];
  __shared__ unsigned short Bl[2][128 * BK];
  const int nwg = gridDim.x;
  const int bid = blockIdx.x;
  const int lin = (bid & 7) * (nwg >> 3) + (bid >> 3);  // bijective (nwg%8==0)
  const int m0 = (lin / nwgn) * 128, n0 = (lin % nwgn) * 128;
  const int tid = threadIdx.x;
  const int w = tid >> 6, lane = tid & 63;
  const int lr = lane & 15, lg = lane >> 4;
  const int wm = (w >> 1) * 64, wn = (w & 1) * 64;
  const int tr = tid >> 3, tc = tid & 7;

  f32x4 acc[4][4];
#pragma unroll
  for (int i = 0; i < 4; ++i)
#pragma unroll
    for (int j = 0; j < 4; ++j) acc[i][j] = (f32x4){0.f, 0.f, 0.f, 0.f};

  // prologue: two tiles in flight (16 glds/thread outstanding)
  stage_tile(A, &Al[0][0], m0, 0, tr, tc, w);
  stage_tile(Bm, &Bl[0][0], n0, 0, tr, tc, w);
  stage_tile(A, &Al[1][0], m0, BK, tr, tc, w);
  stage_tile(Bm, &Bl[1][0], n0, BK, tr, tc, w);

  int cur = 0;
  for (int t = 0; t < NT; ++t) {
    if (t < NT - 1) {
      asm volatile("s_waitcnt vmcnt(8)" ::: "memory");  // buf[cur] landed
    } else {
      asm volatile("s_waitcnt vmcnt(0)" ::: "memory");
    }
    asm volatile("s_barrier" ::: "memory");             // all waves agree
#pragma unroll
    for (int kc = 0; kc < 2; ++kc) {
      us8 af[4], bfr[4];
#pragma unroll
      for (int i = 0; i < 4; ++i) {
        const int ra = wm + i * 16 + lr;
        af[i] = *(const us8*)&Al[cur][ra * 64 + (((kc * 4 + lg) ^ (ra & 7)) * 8)];
        const int rb = wn + i * 16 + lr;
        bfr[i] = *(const us8*)&Bl[cur][rb * 64 + (((kc * 4 + lg) ^ (rb & 7)) * 8)];
      }
#pragma unroll
      for (int i = 0; i < 4; ++i)
#pragma unroll
        for (int j = 0; j < 4; ++j)
          acc[i][j] = mfma16(af[i], bfr[j], acc[i][j]);
    }
    asm volatile("s_barrier" ::: "memory");  // reads of buf[cur] done
    if (t + 2 < NT) {
      stage_tile(A, &Al[cur][0], m0, (t + 2) * BK, tr, tc, w);
      stage_tile(Bm, &Bl[cur][0], n0, (t + 2) * BK, tr, tc, w);
    }
    cur ^= 1;
  }

  // epilogue: C/D frag row=(lane>>4)*4+r, col=lane&15
  if (MODE == 1) {
#pragma unroll
    for (int i = 0; i < 4; ++i)
#pragma unroll
      for (int j = 0; j < 4; ++j) {
        const int col = n0 + wn + j * 16 + lr;
        const float bv = bias[col];
#pragma unroll
        for (int r = 0; r < 4; ++r) {
          const size_t row = m0 + wm + i * 16 + lg * 4 + r;
          Of[row * C + col] = acc[i][j][r] + bv;
        }
      }
  } else if (n0 < 2 * C) {  // Q,K region (Q scaled into log2 domain)
    const float scl = (n0 < C) ? 0.18033688f : 1.0f;  // 0.125 * log2(e)
#pragma unroll
    for (int i = 0; i < 4; ++i)
#pragma unroll
      for (int j = 0; j < 4; ++j) {
        const int col = n0 + wn + j * 16 + lr;
#pragma unroll
        for (int r = 0; r < 4; ++r) {
          const size_t row = m0 + wm + i * 16 + lg * 4 + r;
          QKV[row * NQKV + col] = f2bf(acc[i][j][r] * scl);
        }
      }
  } else {                  // V region: store transposed VT[b][h][d][t]
#pragma unroll
    for (int i = 0; i < 4; ++i)
#pragma unroll
      for (int j = 0; j < 4; ++j) {
        const int vcol = n0 + wn + j * 16 + lr - 2 * C;
        const int h = vcol >> 6, d = vcol & 63;
        const int row0 = m0 + wm + i * 16 + lg * 4;
        const int b = row0 >> 8, tq = row0 & 255;
        us4 o4;
#pragma unroll
        for (int r = 0; r < 4; ++r) o4[r] = f2bf(acc[i][j][r]);
        *(us4*)&VT[(((size_t)b * H + h) * D + d) * T + tq] = o4;
      }
  }
}

// ---------------------------------------------------------------------------
// Fused causal attention, 2-tile flash pipeline (R12-proven structure).
// Scores arrive in log2 domain (Q pre-scaled) -> raw v_exp_f32 softmax.
// Mask skipped on never-masked tiles (tt < qt).
// ---------------------------------------------------------------------------
__global__ __launch_bounds__(512, 4) void k_attn(
    const unsigned short* __restrict__ QKV, const unsigned short* __restrict__ VT,
    unsigned short* __restrict__ Y) {
  __shared__ unsigned short Kl[2][128][64];   // 32KB
  __shared__ unsigned short Vl[2][64][128];   // 32KB
  __shared__ unsigned short Pch[8][16][32];   // 8KB
  const int bid = blockIdx.x;
  const int lin = (bid & 7) * 96 + (bid >> 3);   // bijective: 768 % 8 == 0
  const int b = lin / 12, rr = lin % 12;
  const int h = rr >> 1, qt = rr & 1;
  const int t0 = qt * 128;
  const int nt = qt + 1;
  const int tid = threadIdx.x;
  const int w = tid >> 6, lane = tid & 63;
  const int lr = lane & 15, lg = lane >> 4;
  const int xk = lr & 7;

  // ---- Q fragments first (oldest in vmcnt FIFO) ----
  const size_t qbase = (size_t)(b * T + t0 + w * 16 + lr) * NQKV + h * D;
  const us8 aq0 = *(const us8*)(QKV + qbase + lg * 8);
  const us8 aq1 = *(const us8*)(QKV + qbase + 32 + lg * 8);
  asm volatile("" ::: "memory");   // pin: Q loads issue before staging glds

  const unsigned short* kgbase = QKV + (size_t)(b * T) * NQKV + C + h * D;
  const unsigned short* vbase = VT + ((size_t)b * H + h) * D * T;

  // stage tile tt into buffer tt (K: 2 glds, V: 2 glds per thread)
  auto stage_kv = [&](int tt) {
#pragma unroll
    for (int s = 0; s < 2; ++s) {
      const int row = s * 64 + w * 8 + (lane >> 3);       // 0..127 in tile
      glds16(kgbase + (size_t)(tt * 128 + row) * NQKV + ((lane & 7) ^ (row & 7)) * 8,
             &Kl[tt][s * 64 + w * 8][0]);
    }
#pragma unroll
    for (int s = 0; s < 2; ++s) {
      const int d = s * 32 + w * 4 + (lane >> 4);          // 0..63
      glds16(vbase + (size_t)d * T + tt * 128 + (((lane & 15) ^ (d & 7)) * 8),
             &Vl[tt][s * 32 + w * 4][0]);
    }
  };

  stage_kv(0);
  if (nt == 2) stage_kv(1);

  if (nt == 2) asm volatile("s_waitcnt vmcnt(4)" ::: "memory");  // tile0 ready
  else         asm volatile("s_waitcnt vmcnt(0)" ::: "memory");
  asm volatile("s_barrier" ::: "memory");

  // ---- running softmax state (log2 domain) ----
  float m[4] = {-1e30f, -1e30f, -1e30f, -1e30f};
  float l[4] = {0.f, 0.f, 0.f, 0.f};
  f32x4 o[4];
#pragma unroll
  for (int nf = 0; nf < 4; ++nf) o[nf] = (f32x4){0.f, 0.f, 0.f, 0.f};

  auto process_tile = [&](int tt, bool need_mask) {
    // S = Q K^T over this 128-col tile (already log2-scaled via Q)
    f32x4 s[8];
#pragma unroll
    for (int sf = 0; sf < 8; ++sf) s[sf] = (f32x4){0.f, 0.f, 0.f, 0.f};
#pragma unroll
    for (int sf = 0; sf < 8; ++sf) {
      us8 kb0 = *(const us8*)&Kl[tt][sf * 16 + lr][(lg ^ xk) * 8];
      s[sf] = mfma16(aq0, kb0, s[sf]);
      us8 kb1 = *(const us8*)&Kl[tt][sf * 16 + lr][((4 + lg) ^ xk) * 8];
      s[sf] = mfma16(aq1, kb1, s[sf]);
    }
    // causal mask (uniform-skippable) + tile row-max
    float tm[4] = {-1e30f, -1e30f, -1e30f, -1e30f};
#pragma unroll
    for (int sf = 0; sf < 8; ++sf) {
#pragma unroll
      for (int r = 0; r < 4; ++r) {
        float v = s[sf][r];
        if (need_mask) {
          const int trow = t0 + w * 16 + lg * 4 + r;
          const int scol = tt * 128 + sf * 16 + lr;
          if (scol > trow) v = -1e30f;
          s[sf][r] = v;
        }
        tm[r] = fmaxf(tm[r], v);
      }
    }
#pragma unroll
    for (int dd = 1; dd < 16; dd <<= 1)
#pragma unroll
      for (int r = 0; r < 4; ++r)
        tm[r] = fmaxf(tm[r], __shfl_xor(tm[r], dd, 64));
    // online update: new max, rescale factor (base 2)
    float fac[4];
#pragma unroll
    for (int r = 0; r < 4; ++r) {
      const float mn = fmaxf(m[r], tm[r]);
      fac[r] = __builtin_amdgcn_exp2f(m[r] - mn);
      m[r] = mn;
    }
    // exp2 + tile row-sum
    float ts[4] = {0.f, 0.f, 0.f, 0.f};
#pragma unroll
    for (int sf = 0; sf < 8; ++sf) {
#pragma unroll
      for (int r = 0; r < 4; ++r) {
        float p = __builtin_amdgcn_exp2f(s[sf][r] - m[r]);
        s[sf][r] = p;
        ts[r] += p;
      }
    }
#pragma unroll
    for (int dd = 1; dd < 16; dd <<= 1)
#pragma unroll
      for (int r = 0; r < 4; ++r)
        ts[r] += __shfl_xor(ts[r], dd, 64);
#pragma unroll
    for (int r = 0; r < 4; ++r) l[r] = l[r] * fac[r] + ts[r];
#pragma unroll
    for (int nf = 0; nf < 4; ++nf)
#pragma unroll
      for (int r = 0; r < 4; ++r) o[nf][r] *= fac[r];
    // O += P V over 4 32-col chunks
#pragma unroll
    for (int kk = 0; kk < 4; ++kk) {
#pragma unroll
      for (int half = 0; half < 2; ++half) {
        const int sf = kk * 2 + half;
        const int row = lg * 4;
#pragma unroll
        for (int r = 0; r < 4; ++r) {
          const int cch = (half * 2 + (lr >> 3)) ^ ((row + r) & 3);
          Pch[w][row + r][cch * 8 + (lr & 7)] = f2bf(s[sf][r]);
        }
      }
      __builtin_amdgcn_wave_barrier();
      us8 pa = *(const us8*)&Pch[w][lr][(lg ^ (lr & 3)) * 8];
      __builtin_amdgcn_wave_barrier();
#pragma unroll
      for (int nf = 0; nf < 4; ++nf) {
        us8 bv = *(const us8*)&Vl[tt][nf * 16 + lr][((kk * 4 + lg) ^ xk) * 8];
        o[nf] = mfma16(pa, bv, o[nf]);
      }
    }
  };

  process_tile(0, qt == 0);
  if (nt == 2) {
    asm volatile("s_waitcnt vmcnt(0)" ::: "memory");  // tile1 landed
    asm volatile("s_barrier" ::: "memory");           // all waves' glds visible
    process_tile(1, true);
  }

  // ---- normalize + store ----
  float rs[4];
#pragma unroll
  for (int r = 0; r < 4; ++r) rs[r] = 1.0f / l[r];
#pragma unroll
  for (int nf = 0; nf < 4; ++nf)
#pragma unroll
    for (int r = 0; r < 4; ++r) {
      const int trow = t0 + w * 16 + lg * 4 + r;
      Y[(size_t)(b * T + trow) * C + h * D + nf * 16 + lr] =
          f2bf(o[nf][r] * rs[r]);
    }
}

extern "C" void kernel_launch(void* const* d_in, const int* in_sizes, int n_in,
                              void* d_out, int out_size, void* d_ws, size_t ws_size,
                              hipStream_t stream) {
  const float* x  = (const float*)d_in[0];
  const float* Wq = (const float*)d_in[1];
  const float* Wk = (const float*)d_in[2];
  const float* Wv = (const float*)d_in[3];
  const float* Wp = (const float*)d_in[4];
  const float* bp = (const float*)d_in[5];
  float* out = (float*)d_out;

  unsigned short* Wall = (unsigned short*)d_ws;             //   884,736 B
  unsigned short* Wpb  = Wall + WALL_ELEMS;                 //   294,912 B
  unsigned short* QKV  = Wpb + WP_ELEMS;                    //  37,748,736 B
  unsigned short* Yb   = QKV + (size_t)BT * NQKV;           //  12,582,912 B
  unsigned short* VT   = Yb + (size_t)BT * C;               //  12,582,912 B
  unsigned short* Xb   = Yb;  // alias: Xb dead before k_attn writes Yb

  k_prep<<<180 + BT * C / 2048, 256, 0, stream>>>(x, Wq, Wk, Wv, Wp,
                                                  Wall, Wpb, Xb);
  k_gemm<0><<<NQKV / 128 * (BT / 128), 256, 0, stream>>>(
      Xb, Wall, nullptr, QKV, VT, nullptr, NQKV / 128);
  k_attn<<<T / 128 * H * Bn, 512, 0, stream>>>(QKV, VT, Yb);
  k_gemm<1><<<C / 128 * (BT / 128), 256, 0, stream>>>(
      Yb, Wpb, bp, nullptr, nullptr, out, C / 128);
}

// Round 22
// 66.788 us; speedup vs baseline: 1.0049x; 1.0004x over previous
//
#include <hip/hip_runtime.h>

constexpr int Bn = 64, T = 256, C = 384, H = 6, D = 64;
constexpr int BT = Bn * T;          // 16384
constexpr int NQKV = 3 * C;         // 1152
constexpr int WALL_ELEMS = NQKV * C; // 442368
constexpr int WP_ELEMS = C * C;      // 147456

using f32x4 = __attribute__((ext_vector_type(4))) float;
using fvec4 = __attribute__((ext_vector_type(4))) float;
using us4   = __attribute__((ext_vector_type(4))) unsigned short;
using us8   = __attribute__((ext_vector_type(8))) unsigned short;
using bf8   = __attribute__((ext_vector_type(8))) __bf16;

__device__ __forceinline__ unsigned short f2bf(float f) {
  unsigned u = __builtin_bit_cast(unsigned, f);
  u += 0x7FFFu + ((u >> 16) & 1u);   // RNE; inputs are never NaN here
  return (unsigned short)(u >> 16);
}

__device__ __forceinline__ f32x4 mfma16(us8 a, us8 b, f32x4 c) {
  return __builtin_amdgcn_mfma_f32_16x16x32_bf16(
      __builtin_bit_cast(bf8, a), __builtin_bit_cast(bf8, b), c, 0, 0, 0);
}

__device__ __forceinline__ void glds16(const unsigned short* g,
                                       unsigned short* l) {
  __builtin_amdgcn_global_load_lds(
      (const __attribute__((address_space(1))) unsigned int*)g,
      (__attribute__((address_space(3))) unsigned int*)l, 16, 0, 0);
}

// ---------------------------------------------------------------------------
// Prep (one launch): blocks 0..107 transpose Wq/Wk/Wv -> Wall_t[n][c];
// blocks 108..179 cast Wp -> Wpb; blocks 180..3251 cast x -> Xb.
// ---------------------------------------------------------------------------
__global__ __launch_bounds__(256) void k_prep(
    const float* __restrict__ x,
    const float* __restrict__ Wq, const float* __restrict__ Wk,
    const float* __restrict__ Wv, const float* __restrict__ Wp,
    unsigned short* __restrict__ Wall, unsigned short* __restrict__ Wpb,
    unsigned short* __restrict__ Xb) {
  __shared__ unsigned short t[64][71];
  const int bid = blockIdx.x;
  const int tid = threadIdx.x;
  if (bid < 108) {
    const int ct = bid % 6, ph = bid / 6;
    const int h = ph % 6, p = ph / 6;
    const float* W = (p == 0) ? Wq : (p == 1) ? Wk : Wv;
    const int c0 = ct * 64;
    const int d = tid & 63, cq = tid >> 6;
#pragma unroll
    for (int s = 0; s < 16; ++s) {
      const int c_loc = cq * 16 + s;
      t[c_loc][d] = f2bf(W[(size_t)(h * C + c0 + c_loc) * D + d]);
    }
    __syncthreads();
    const int d_loc = tid >> 2, ch = tid & 3;
#pragma unroll
    for (int it = 0; it < 2; ++it) {
      const int cc = (ch + it * 4) * 8;
      us8 o;
#pragma unroll
      for (int j = 0; j < 8; ++j) o[j] = t[cc + j][d_loc];
      *(us8*)&Wall[(size_t)(p * C + h * D + d_loc) * C + c0 + cc] = o;
    }
  } else {
    const float* src;
    unsigned short* dst;
    int off;
    if (bid < 180) { src = Wp; dst = Wpb; off = (bid - 108) * 2048 + tid * 8; }
    else           { src = x;  dst = Xb;  off = (bid - 180) * 2048 + tid * 8; }
    fvec4 a = *(const fvec4*)(src + off);
    fvec4 b = *(const fvec4*)(src + off + 4);
    us8 o;
#pragma unroll
    for (int j = 0; j < 4; ++j) { o[j] = f2bf(a[j]); o[4 + j] = f2bf(b[j]); }
    *(us8*)(dst + off) = o;
  }
}

// ---------------------------------------------------------------------------
// Staging for BK=64 tiles (128 rows x 64 cols bf16 = 16KB): global_load_lds
// w=16, XOR-swizzled SOURCE (LDS chunk position c holds global chunk
// c^(row&7); linear LDS dest). 4 instructions per thread per tile.
// ---------------------------------------------------------------------------
__device__ __forceinline__ void stage_tile(
    const unsigned short* __restrict__ g, unsigned short* l,
    int row0g, int k0, int tr, int tc, int w) {
#pragma unroll
  for (int s = 0; s < 4; ++s) {
    const int row = s * 32 + tr;                  // tr = tid>>3 (0..31)
    const int sc = (tc ^ (row & 7)) * 8;          // tc = tid&7
    glds16(g + (size_t)(row0g + row) * C + k0 + sc,
           l + (s * 32 + w * 8) * 64);            // wave-uniform base
  }
}

// ---------------------------------------------------------------------------
// Double-buffered 128x128 GEMM, BK=64, counted-vmcnt pipeline (R10/R14-proven
// best). MODE 0: A=Xb, B=Wall -> QKV bf16 (Q pre-scaled by 0.125*log2e;
// V transposed into VT). MODE 1: A=Yb, B=Wpb -> out f32 + bias.
// ---------------------------------------------------------------------------
template <int MODE>
__global__ __launch_bounds__(256) void k_gemm(
    const unsigned short* __restrict__ A, const unsigned short* __restrict__ Bm,
    const float* __restrict__ bias, unsigned short* __restrict__ QKV,
    unsigned short* __restrict__ VT, float* __restrict__ Of, int nwgn) {
  constexpr int BK = 64, NT = C / BK;   // 6 K-steps
  __shared__ unsigned short Al[2][128 * BK];
  __shared__ unsigned short Bl[2][128 * BK];
  const int nwg = gridDim.x;
  const int bid = blockIdx.x;
  const int lin = (bid & 7) * (nwg >> 3) + (bid >> 3);  // bijective (nwg%8==0)
  const int m0 = (lin / nwgn) * 128, n0 = (lin % nwgn) * 128;
  const int tid = threadIdx.x;
  const int w = tid >> 6, lane = tid & 63;
  const int lr = lane & 15, lg = lane >> 4;
  const int wm = (w >> 1) * 64, wn = (w & 1) * 64;
  const int tr = tid >> 3, tc = tid & 7;

  f32x4 acc[4][4];
#pragma unroll
  for (int i = 0; i < 4; ++i)
#pragma unroll
    for (int j = 0; j < 4; ++j) acc[i][j] = (f32x4){0.f, 0.f, 0.f, 0.f};

  // prologue: two tiles in flight (16 glds/thread outstanding)
  stage_tile(A, &Al[0][0], m0, 0, tr, tc, w);
  stage_tile(Bm, &Bl[0][0], n0, 0, tr, tc, w);
  stage_tile(A, &Al[1][0], m0, BK, tr, tc, w);
  stage_tile(Bm, &Bl[1][0], n0, BK, tr, tc, w);

  int cur = 0;
  for (int t = 0; t < NT; ++t) {
    if (t < NT - 1) {
      asm volatile("s_waitcnt vmcnt(8)" ::: "memory");  // buf[cur] landed
    } else {
      asm volatile("s_waitcnt vmcnt(0)" ::: "memory");
    }
    asm volatile("s_barrier" ::: "memory");             // all waves agree
#pragma unroll
    for (int kc = 0; kc < 2; ++kc) {
      us8 af[4], bfr[4];
#pragma unroll
      for (int i = 0; i < 4; ++i) {
        const int ra = wm + i * 16 + lr;
        af[i] = *(const us8*)&Al[cur][ra * 64 + (((kc * 4 + lg) ^ (ra & 7)) * 8)];
        const int rb = wn + i * 16 + lr;
        bfr[i] = *(const us8*)&Bl[cur][rb * 64 + (((kc * 4 + lg) ^ (rb & 7)) * 8)];
      }
#pragma unroll
      for (int i = 0; i < 4; ++i)
#pragma unroll
        for (int j = 0; j < 4; ++j)
          acc[i][j] = mfma16(af[i], bfr[j], acc[i][j]);
    }
    asm volatile("s_barrier" ::: "memory");  // reads of buf[cur] done
    if (t + 2 < NT) {
      stage_tile(A, &Al[cur][0], m0, (t + 2) * BK, tr, tc, w);
      stage_tile(Bm, &Bl[cur][0], n0, (t + 2) * BK, tr, tc, w);
    }
    cur ^= 1;
  }

  // epilogue: C/D frag row=(lane>>4)*4+r, col=lane&15
  if (MODE == 1) {
#pragma unroll
    for (int i = 0; i < 4; ++i)
#pragma unroll
      for (int j = 0; j < 4; ++j) {
        const int col = n0 + wn + j * 16 + lr;
        const float bv = bias[col];
#pragma unroll
        for (int r = 0; r < 4; ++r) {
          const size_t row = m0 + wm + i * 16 + lg * 4 + r;
          Of[row * C + col] = acc[i][j][r] + bv;
        }
      }
  } else if (n0 < 2 * C) {  // Q,K region (Q scaled into log2 domain)
    const float scl = (n0 < C) ? 0.18033688f : 1.0f;  // 0.125 * log2(e)
#pragma unroll
    for (int i = 0; i < 4; ++i)
#pragma unroll
      for (int j = 0; j < 4; ++j) {
        const int col = n0 + wn + j * 16 + lr;
#pragma unroll
        for (int r = 0; r < 4; ++r) {
          const size_t row = m0 + wm + i * 16 + lg * 4 + r;
          QKV[row * NQKV + col] = f2bf(acc[i][j][r] * scl);
        }
      }
  } else {                  // V region: store transposed VT[b][h][d][t]
#pragma unroll
    for (int i = 0; i < 4; ++i)
#pragma unroll
      for (int j = 0; j < 4; ++j) {
        const int vcol = n0 + wn + j * 16 + lr - 2 * C;
        const int h = vcol >> 6, d = vcol & 63;
        const int row0 = m0 + wm + i * 16 + lg * 4;
        const int b = row0 >> 8, tq = row0 & 255;
        us4 o4;
#pragma unroll
        for (int r = 0; r < 4; ++r) o4[r] = f2bf(acc[i][j][r]);
        *(us4*)&VT[(((size_t)b * H + h) * D + d) * T + tq] = o4;
      }
  }
}

// ---------------------------------------------------------------------------
// Fused causal attention, 2-tile flash pipeline (R12-proven structure).
// Scores arrive in log2 domain (Q pre-scaled) -> raw v_exp_f32 softmax.
// Mask skipped on never-masked tiles (tt < qt).
// ---------------------------------------------------------------------------
__global__ __launch_bounds__(512, 4) void k_attn(
    const unsigned short* __restrict__ QKV, const unsigned short* __restrict__ VT,
    unsigned short* __restrict__ Y) {
  __shared__ unsigned short Kl[2][128][64];   // 32KB
  __shared__ unsigned short Vl[2][64][128];   // 32KB
  __shared__ unsigned short Pch[8][16][32];   // 8KB
  const int bid = blockIdx.x;
  const int lin = (bid & 7) * 96 + (bid >> 3);   // bijective: 768 % 8 == 0
  const int b = lin / 12, rr = lin % 12;
  const int h = rr >> 1, qt = rr & 1;
  const int t0 = qt * 128;
  const int nt = qt + 1;
  const int tid = threadIdx.x;
  const int w = tid >> 6, lane = tid & 63;
  const int lr = lane & 15, lg = lane >> 4;
  const int xk = lr & 7;

  // ---- Q fragments first (oldest in vmcnt FIFO) ----
  const size_t qbase = (size_t)(b * T + t0 + w * 16 + lr) * NQKV + h * D;
  const us8 aq0 = *(const us8*)(QKV + qbase + lg * 8);
  const us8 aq1 = *(const us8*)(QKV + qbase + 32 + lg * 8);
  asm volatile("" ::: "memory");   // pin: Q loads issue before staging glds

  const unsigned short* kgbase = QKV + (size_t)(b * T) * NQKV + C + h * D;
  const unsigned short* vbase = VT + ((size_t)b * H + h) * D * T;

  // stage tile tt into buffer tt (K: 2 glds, V: 2 glds per thread)
  auto stage_kv = [&](int tt) {
#pragma unroll
    for (int s = 0; s < 2; ++s) {
      const int row = s * 64 + w * 8 + (lane >> 3);       // 0..127 in tile
      glds16(kgbase + (size_t)(tt * 128 + row) * NQKV + ((lane & 7) ^ (row & 7)) * 8,
             &Kl[tt][s * 64 + w * 8][0]);
    }
#pragma unroll
    for (int s = 0; s < 2; ++s) {
      const int d = s * 32 + w * 4 + (lane >> 4);          // 0..63
      glds16(vbase + (size_t)d * T + tt * 128 + (((lane & 15) ^ (d & 7)) * 8),
             &Vl[tt][s * 32 + w * 4][0]);
    }
  };

  stage_kv(0);
  if (nt == 2) stage_kv(1);

  if (nt == 2) asm volatile("s_waitcnt vmcnt(4)" ::: "memory");  // tile0 ready
  else         asm volatile("s_waitcnt vmcnt(0)" ::: "memory");
  asm volatile("s_barrier" ::: "memory");

  // ---- running softmax state (log2 domain) ----
  float m[4] = {-1e30f, -1e30f, -1e30f, -1e30f};
  float l[4] = {0.f, 0.f, 0.f, 0.f};
  f32x4 o[4];
#pragma unroll
  for (int nf = 0; nf < 4; ++nf) o[nf] = (f32x4){0.f, 0.f, 0.f, 0.f};

  auto process_tile = [&](int tt, bool need_mask) {
    // S = Q K^T over this 128-col tile (already log2-scaled via Q)
    f32x4 s[8];
#pragma unroll
    for (int sf = 0; sf < 8; ++sf) s[sf] = (f32x4){0.f, 0.f, 0.f, 0.f};
#pragma unroll
    for (int sf = 0; sf < 8; ++sf) {
      us8 kb0 = *(const us8*)&Kl[tt][sf * 16 + lr][(lg ^ xk) * 8];
      s[sf] = mfma16(aq0, kb0, s[sf]);
      us8 kb1 = *(const us8*)&Kl[tt][sf * 16 + lr][((4 + lg) ^ xk) * 8];
      s[sf] = mfma16(aq1, kb1, s[sf]);
    }
    // causal mask (uniform-skippable) + tile row-max
    float tm[4] = {-1e30f, -1e30f, -1e30f, -1e30f};
#pragma unroll
    for (int sf = 0; sf < 8; ++sf) {
#pragma unroll
      for (int r = 0; r < 4; ++r) {
        float v = s[sf][r];
        if (need_mask) {
          const int trow = t0 + w * 16 + lg * 4 + r;
          const int scol = tt * 128 + sf * 16 + lr;
          if (scol > trow) v = -1e30f;
          s[sf][r] = v;
        }
        tm[r] = fmaxf(tm[r], v);
      }
    }
#pragma unroll
    for (int dd = 1; dd < 16; dd <<= 1)
#pragma unroll
      for (int r = 0; r < 4; ++r)
        tm[r] = fmaxf(tm[r], __shfl_xor(tm[r], dd, 64));
    // online update: new max, rescale factor (base 2)
    float fac[4];
#pragma unroll
    for (int r = 0; r < 4; ++r) {
      const float mn = fmaxf(m[r], tm[r]);
      fac[r] = __builtin_amdgcn_exp2f(m[r] - mn);
      m[r] = mn;
    }
    // exp2 + tile row-sum
    float ts[4] = {0.f, 0.f, 0.f, 0.f};
#pragma unroll
    for (int sf = 0; sf < 8; ++sf) {
#pragma unroll
      for (int r = 0; r < 4; ++r) {
        float p = __builtin_amdgcn_exp2f(s[sf][r] - m[r]);
        s[sf][r] = p;
        ts[r] += p;
      }
    }
#pragma unroll
    for (int dd = 1; dd < 16; dd <<= 1)
#pragma unroll
      for (int r = 0; r < 4; ++r)
        ts[r] += __shfl_xor(ts[r], dd, 64);
#pragma unroll
    for (int r = 0; r < 4; ++r) l[r] = l[r] * fac[r] + ts[r];
#pragma unroll
    for (int nf = 0; nf < 4; ++nf)
#pragma unroll
      for (int r = 0; r < 4; ++r) o[nf][r] *= fac[r];
    // O += P V over 4 32-col chunks
#pragma unroll
    for (int kk = 0; kk < 4; ++kk) {
#pragma unroll
      for (int half = 0; half < 2; ++half) {
        const int sf = kk * 2 + half;
        const int row = lg * 4;
#pragma unroll
        for (int r = 0; r < 4; ++r) {
          const int cch = (half * 2 + (lr >> 3)) ^ ((row + r) & 3);
          Pch[w][row + r][cch * 8 + (lr & 7)] = f2bf(s[sf][r]);
        }
      }
      __builtin_amdgcn_wave_barrier();
      us8 pa = *(const us8*)&Pch[w][lr][(lg ^ (lr & 3)) * 8];
      __builtin_amdgcn_wave_barrier();
#pragma unroll
      for (int nf = 0; nf < 4; ++nf) {
        us8 bv = *(const us8*)&Vl[tt][nf * 16 + lr][((kk * 4 + lg) ^ xk) * 8];
        o[nf] = mfma16(pa, bv, o[nf]);
      }
    }
  };

  process_tile(0, qt == 0);
  if (nt == 2) {
    asm volatile("s_waitcnt vmcnt(0)" ::: "memory");  // tile1 landed
    asm volatile("s_barrier" ::: "memory");           // all waves' glds visible
    process_tile(1, true);
  }

  // ---- normalize + store ----
  float rs[4];
#pragma unroll
  for (int r = 0; r < 4; ++r) rs[r] = 1.0f / l[r];
#pragma unroll
  for (int nf = 0; nf < 4; ++nf)
#pragma unroll
    for (int r = 0; r < 4; ++r) {
      const int trow = t0 + w * 16 + lg * 4 + r;
      Y[(size_t)(b * T + trow) * C + h * D + nf * 16 + lr] =
          f2bf(o[nf][r] * rs[r]);
    }
}

extern "C" void kernel_launch(void* const* d_in, const int* in_sizes, int n_in,
                              void* d_out, int out_size, void* d_ws, size_t ws_size,
                              hipStream_t stream) {
  const float* x  = (const float*)d_in[0];
  const float* Wq = (const float*)d_in[1];
  const float* Wk = (const float*)d_in[2];
  const float* Wv = (const float*)d_in[3];
  const float* Wp = (const float*)d_in[4];
  const float* bp = (const float*)d_in[5];
  float* out = (float*)d_out;

  unsigned short* Wall = (unsigned short*)d_ws;             //   884,736 B
  unsigned short* Wpb  = Wall + WALL_ELEMS;                 //   294,912 B
  unsigned short* QKV  = Wpb + WP_ELEMS;                    //  37,748,736 B
  unsigned short* Yb   = QKV + (size_t)BT * NQKV;           //  12,582,912 B
  unsigned short* VT   = Yb + (size_t)BT * C;               //  12,582,912 B
  unsigned short* Xb   = Yb;  // alias: Xb dead before k_attn writes Yb

  k_prep<<<180 + BT * C / 2048, 256, 0, stream>>>(x, Wq, Wk, Wv, Wp,
                                                  Wall, Wpb, Xb);
  k_gemm<0><<<NQKV / 128 * (BT / 128), 256, 0, stream>>>(
      Xb, Wall, nullptr, QKV, VT, nullptr, NQKV / 128);
  k_attn<<<T / 128 * H * Bn, 512, 0, stream>>>(QKV, VT, Yb);
  k_gemm<1><<<C / 128 * (BT / 128), 256, 0, stream>>>(
      Yb, Wpb, bp, nullptr, nullptr, out, C / 128);
}